// Round 3
// baseline (1350.007 us; speedup 1.0000x reference)
//
#include <hip/hip_runtime.h>
#include <hip/hip_bf16.h>
#include <hip/hip_fp16.h>

#define N_NODES 100000
#define N_EDGES 3200000
#define NFEAT 512
#define HDIM 64
#define NCLASS 40
#define N_LAYERS 4
#define NEG_SLOPE 0.2f

#define NPB 64                       // nodes per bucket (power of 2)
#define NB ((N_NODES + NPB - 1) / NPB)   // 1563 buckets

__device__ __forceinline__ float leaky(float x) {
    return x >= 0.f ? x : NEG_SLOPE * x;
}

// ---------------- CSR build ----------------

__global__ void histo_kernel(const int* __restrict__ ei, int* __restrict__ deg) {
    int stride = gridDim.x * blockDim.x;
    for (int e = blockIdx.x * blockDim.x + threadIdx.x; e < N_EDGES; e += stride) {
        int d = ei[N_EDGES + e];
        atomicAdd(&deg[d], 1);
    }
}

__global__ __launch_bounds__(1024) void scan_block_kernel(const int* __restrict__ deg,
                                                          int* __restrict__ rp,
                                                          int* __restrict__ bsum, int n) {
    __shared__ int s[1024];
    int t = threadIdx.x;
    int i = blockIdx.x * 1024 + t;
    int v = (i < n) ? deg[i] : 0;
    s[t] = v;
    __syncthreads();
    for (int off = 1; off < 1024; off <<= 1) {
        int x = (t >= off) ? s[t - off] : 0;
        __syncthreads();
        s[t] += x;
        __syncthreads();
    }
    if (i < n) rp[i] = s[t] - v;        // exclusive
    if (t == 1023) bsum[blockIdx.x] = s[t];
}

__global__ __launch_bounds__(1024) void scan_partials_kernel(int* __restrict__ bsum, int nb) {
    __shared__ int s[1024];
    int t = threadIdx.x;
    int v = (t < nb) ? bsum[t] : 0;
    s[t] = v;
    __syncthreads();
    for (int off = 1; off < 1024; off <<= 1) {
        int x = (t >= off) ? s[t - off] : 0;
        __syncthreads();
        s[t] += x;
        __syncthreads();
    }
    if (t < nb) bsum[t] = s[t] - v;     // exclusive
}

__global__ void fixup_kernel(int* __restrict__ rp, const int* __restrict__ bsum, int n) {
    int i = blockIdx.x * blockDim.x + threadIdx.x;
    if (i < n) rp[i] = rp[i] + bsum[i >> 10];
    if (i == n) rp[n] = N_EDGES;
}

__global__ void init_bcursor_kernel(const int* __restrict__ rp, int* __restrict__ bcur) {
    int b = blockIdx.x * blockDim.x + threadIdx.x;
    if (b < NB) bcur[b] = rp[b * NPB];
}

// Phase A: partition edges into dst-buckets; stores within a bucket are at
// sequentially increasing addresses -> dense cache-line fill, ~data-size writes.
__global__ void partition_kernel(const int* __restrict__ ei, int* __restrict__ bcur,
                                 int2* __restrict__ pairs) {
    int stride = gridDim.x * blockDim.x;
    for (int e = blockIdx.x * blockDim.x + threadIdx.x; e < N_EDGES; e += stride) {
        int s = ei[e];
        int d = ei[N_EDGES + e];
        int b = d >> 6;   // NPB = 64
        int p = atomicAdd(&bcur[b], 1);
        pairs[p] = make_int2(s, d);
    }
}

// Phase B: one block per bucket; LDS cursors for the bucket's <=64 nodes.
// col stores scatter only within the bucket's small L2-resident window.
__global__ __launch_bounds__(256) void bucket_fill_kernel(const int* __restrict__ rp,
                                                          const int2* __restrict__ pairs,
                                                          int* __restrict__ col) {
    __shared__ int cur[NPB];
    int b = blockIdx.x;
    int nlo = b * NPB;
    int nhi = nlo + NPB; if (nhi > N_NODES) nhi = N_NODES;
    int t = threadIdx.x;
    if (t < nhi - nlo) cur[t] = rp[nlo + t];
    __syncthreads();
    int beg = rp[nlo];
    int end = rp[nhi];
    for (int e = beg + t; e < end; e += 256) {
        int2 pr = pairs[e];
        int p = atomicAdd(&cur[pr.y - nlo], 1);
        col[p] = pr.x;
    }
}

// ---------------- GEMM: C[M x 64] = A[M x K] @ B[K x 64] + bias ----------------
// block 256 = 16x16 threads, tile 64x64, micro-tile 4x4, BK=16

__global__ __launch_bounds__(256) void gemm_rt(const float* __restrict__ A,
                                               const float* __restrict__ B,
                                               const float* __restrict__ bias,
                                               float* __restrict__ C, int M, int K) {
    __shared__ float As[16][65];  // [k][m], padded
    __shared__ float Bs[16][64];  // [k][n]
    int t = threadIdx.x;
    int tx = t & 15;
    int ty = t >> 4;
    int row0 = blockIdx.x * 64;
    float acc[4][4] = {};
    for (int kt = 0; kt < K; kt += 16) {
        {
            int r = t >> 2;
            int kk = (t & 3) << 2;
            int gr = row0 + r;
            float4 v = make_float4(0.f, 0.f, 0.f, 0.f);
            if (gr < M) v = *(const float4*)&A[(size_t)gr * K + kt + kk];
            As[kk + 0][r] = v.x;
            As[kk + 1][r] = v.y;
            As[kk + 2][r] = v.z;
            As[kk + 3][r] = v.w;
        }
        {
            int kk = t >> 4;
            int n0 = (t & 15) << 2;
            float4 v = *(const float4*)&B[(size_t)(kt + kk) * 64 + n0];
            *(float4*)&Bs[kk][n0] = v;
        }
        __syncthreads();
#pragma unroll
        for (int kk = 0; kk < 16; ++kk) {
            float a0 = As[kk][ty * 4 + 0];
            float a1 = As[kk][ty * 4 + 1];
            float a2 = As[kk][ty * 4 + 2];
            float a3 = As[kk][ty * 4 + 3];
            float4 b = *(float4*)&Bs[kk][tx * 4];
            acc[0][0] += a0 * b.x; acc[0][1] += a0 * b.y; acc[0][2] += a0 * b.z; acc[0][3] += a0 * b.w;
            acc[1][0] += a1 * b.x; acc[1][1] += a1 * b.y; acc[1][2] += a1 * b.z; acc[1][3] += a1 * b.w;
            acc[2][0] += a2 * b.x; acc[2][1] += a2 * b.y; acc[2][2] += a2 * b.z; acc[2][3] += a2 * b.w;
            acc[3][0] += a3 * b.x; acc[3][1] += a3 * b.y; acc[3][2] += a3 * b.z; acc[3][3] += a3 * b.w;
        }
        __syncthreads();
    }
#pragma unroll
    for (int i = 0; i < 4; ++i) {
        int gr = row0 + ty * 4 + i;
        if (gr < M) {
#pragma unroll
            for (int j = 0; j < 4; ++j) {
                int n = tx * 4 + j;
                float bv = bias ? bias[n] : 0.f;
                C[(size_t)gr * 64 + n] = acc[i][j] + bv;
            }
        }
    }
}

// ---------------- fused layer GEMM: h2 = A @ W, + att dots + fp16 convert ----------------
// Writes h2h (fp16 rows) and per-node attention dots as_/ad_. No fp32 h2 buffer.

__global__ __launch_bounds__(256) void gemm_fused(const float* __restrict__ A,
                                                  const float* __restrict__ W,
                                                  const float* __restrict__ att_s_g,
                                                  const float* __restrict__ att_d_g,
                                                  float* __restrict__ as_,
                                                  float* __restrict__ ad_,
                                                  __half* __restrict__ h2h, int M) {
    __shared__ float As[16][65];
    __shared__ float Bs[16][64];
    __shared__ float2 red[64][17];   // padded: avoids bank conflicts in reduce
    __shared__ float sATT[128];
    int t = threadIdx.x;
    int tx = t & 15;
    int ty = t >> 4;
    int row0 = blockIdx.x * 64;
    if (t < 64) sATT[t] = att_s_g[t];
    else if (t < 128) sATT[t] = att_d_g[t - 64];
    float acc[4][4] = {};
    for (int kt = 0; kt < 64; kt += 16) {
        {
            int r = t >> 2;
            int kk = (t & 3) << 2;
            int gr = row0 + r;
            float4 v = make_float4(0.f, 0.f, 0.f, 0.f);
            if (gr < M) v = *(const float4*)&A[(size_t)gr * 64 + kt + kk];
            As[kk + 0][r] = v.x;
            As[kk + 1][r] = v.y;
            As[kk + 2][r] = v.z;
            As[kk + 3][r] = v.w;
        }
        {
            int kk = t >> 4;
            int n0 = (t & 15) << 2;
            float4 v = *(const float4*)&W[(size_t)(kt + kk) * 64 + n0];
            *(float4*)&Bs[kk][n0] = v;
        }
        __syncthreads();
#pragma unroll
        for (int kk = 0; kk < 16; ++kk) {
            float a0 = As[kk][ty * 4 + 0];
            float a1 = As[kk][ty * 4 + 1];
            float a2 = As[kk][ty * 4 + 2];
            float a3 = As[kk][ty * 4 + 3];
            float4 b = *(float4*)&Bs[kk][tx * 4];
            acc[0][0] += a0 * b.x; acc[0][1] += a0 * b.y; acc[0][2] += a0 * b.z; acc[0][3] += a0 * b.w;
            acc[1][0] += a1 * b.x; acc[1][1] += a1 * b.y; acc[1][2] += a1 * b.z; acc[1][3] += a1 * b.w;
            acc[2][0] += a2 * b.x; acc[2][1] += a2 * b.y; acc[2][2] += a2 * b.z; acc[2][3] += a2 * b.w;
            acc[3][0] += a3 * b.x; acc[3][1] += a3 * b.y; acc[3][2] += a3 * b.z; acc[3][3] += a3 * b.w;
        }
        __syncthreads();
    }
    // attention partial dots + reduce across the 16 column-threads of each row
#pragma unroll
    for (int i = 0; i < 4; ++i) {
        float ps = acc[i][0] * sATT[tx * 4 + 0] + acc[i][1] * sATT[tx * 4 + 1] +
                   acc[i][2] * sATT[tx * 4 + 2] + acc[i][3] * sATT[tx * 4 + 3];
        float pd = acc[i][0] * sATT[64 + tx * 4 + 0] + acc[i][1] * sATT[64 + tx * 4 + 1] +
                   acc[i][2] * sATT[64 + tx * 4 + 2] + acc[i][3] * sATT[64 + tx * 4 + 3];
        red[ty * 4 + i][tx] = make_float2(ps, pd);
    }
    __syncthreads();
    if (t < 64) {
        float a = 0.f, b = 0.f;
#pragma unroll
        for (int k = 0; k < 16; ++k) {
            float2 v = red[t][k];
            a += v.x; b += v.y;
        }
        int gr = row0 + t;
        if (gr < M) { as_[gr] = a; ad_[gr] = b; }
    }
    // fp16 store of the tile
    __half2* h2h2 = (__half2*)h2h;
#pragma unroll
    for (int i = 0; i < 4; ++i) {
        int gr = row0 + ty * 4 + i;
        if (gr < M) {
            h2h2[(size_t)gr * 32 + tx * 2 + 0] = __floats2half2_rn(acc[i][0], acc[i][1]);
            h2h2[(size_t)gr * 32 + tx * 2 + 1] = __floats2half2_rn(acc[i][2], acc[i][3]);
        }
    }
}

// ---------------- GAT aggregation: wave per dst node, lane = feature ----------------

__global__ __launch_bounds__(256) void gat_aggregate(const int* __restrict__ rp,
                                                     const int* __restrict__ col,
                                                     const __half* __restrict__ h2h,
                                                     const float* __restrict__ as_,
                                                     const float* __restrict__ ad_,
                                                     const float* __restrict__ bias,
                                                     float* __restrict__ h /* in/out */) {
    int wid = blockIdx.x * (blockDim.x >> 6) + (threadIdx.x >> 6);
    int lane = threadIdx.x & 63;
    if (wid >= N_NODES) return;
    int beg = rp[wid];
    int end = rp[wid + 1];
    float adv = ad_[wid];
    float e_self = leaky(as_[wid] + adv);

    // phase 1: max over incoming edges + self
    float mloc = e_self;
    for (int j = beg + lane; j < end; j += 64) {
        mloc = fmaxf(mloc, leaky(as_[col[j]] + adv));
    }
#pragma unroll
    for (int off = 32; off; off >>= 1) mloc = fmaxf(mloc, __shfl_xor(mloc, off));
    float m = mloc;

    // phase 2: weighted accumulation
    float w_self = __expf(e_self - m);
    float acc = w_self * __half2float(h2h[(size_t)wid * 64 + lane]);
    float wpart = 0.f;
    for (int j0 = beg; j0 < end; j0 += 64) {
        int rem = end - j0;
        int cnt = rem < 64 ? rem : 64;
        int s = 0;
        float w = 0.f;
        if (lane < cnt) {
            s = col[j0 + lane];
            w = __expf(leaky(as_[s] + adv) - m);
        }
        wpart += w;
        int j = 0;
        for (; j + 4 <= cnt; j += 4) {
            float w0 = __shfl(w, j), w1 = __shfl(w, j + 1);
            float w2 = __shfl(w, j + 2), w3 = __shfl(w, j + 3);
            int s0 = __shfl(s, j), s1 = __shfl(s, j + 1);
            int s2 = __shfl(s, j + 2), s3 = __shfl(s, j + 3);
            float v0 = __half2float(h2h[(size_t)s0 * 64 + lane]);
            float v1 = __half2float(h2h[(size_t)s1 * 64 + lane]);
            float v2 = __half2float(h2h[(size_t)s2 * 64 + lane]);
            float v3 = __half2float(h2h[(size_t)s3 * 64 + lane]);
            acc += w0 * v0;
            acc += w1 * v1;
            acc += w2 * v2;
            acc += w3 * v3;
        }
        for (; j < cnt; ++j) {
            float wj = __shfl(w, j);
            int sj = __shfl(s, j);
            acc += wj * __half2float(h2h[(size_t)sj * 64 + lane]);
        }
    }
#pragma unroll
    for (int off = 32; off; off >>= 1) wpart += __shfl_xor(wpart, off);
    float denom = wpart + w_self;

    float o = acc / denom + bias[lane];
    float e = (o > 0.f) ? o : expm1f(o);
    size_t idx = (size_t)wid * 64 + lane;
    h[idx] = h[idx] + e;   // residual, in place (own row only)
}

// ---------------- output GEMM: out[N x 40] = h[N x 64] @ W[64 x 40] + b ----------------

__global__ __launch_bounds__(256) void out_gemm(const float* __restrict__ h,
                                                const float* __restrict__ W,
                                                const float* __restrict__ b,
                                                float* __restrict__ out) {
    __shared__ float Ws[64 * 40];
    __shared__ float bs[40];
    int t = threadIdx.x;
    for (int idx = t; idx < 64 * 40; idx += 256) Ws[idx] = W[idx];
    if (t < 40) bs[t] = b[t];
    __syncthreads();
    int wid = blockIdx.x * (blockDim.x >> 6) + (t >> 6);
    int lane = t & 63;
    if (wid >= N_NODES) return;
    float hv = h[(size_t)wid * 64 + lane];
    float acc = (lane < 40) ? bs[lane] : 0.f;
#pragma unroll
    for (int k = 0; k < 64; ++k) {
        float hk = __shfl(hv, k);
        float wv = (lane < 40) ? Ws[k * 40 + lane] : 0.f;
        acc += hk * wv;
    }
    if (lane < 40) out[(size_t)wid * 40 + lane] = acc;
}

// ---------------- launcher ----------------

extern "C" void kernel_launch(void* const* d_in, const int* in_sizes, int n_in,
                              void* d_out, int out_size, void* d_ws, size_t ws_size,
                              hipStream_t stream) {
    const float* x        = (const float*)d_in[0];
    const int* ei         = (const int*)d_in[1];   // harness passes integers as int32
    const float* W_in     = (const float*)d_in[2];
    const float* b_in     = (const float*)d_in[3];
    const float* W_conv   = (const float*)d_in[4];
    const float* att_src  = (const float*)d_in[5];
    const float* att_dst  = (const float*)d_in[6];
    const float* b_conv   = (const float*)d_in[7];
    const float* W_out    = (const float*)d_in[8];
    const float* b_out    = (const float*)d_in[9];
    float* out = (float*)d_out;

    char* w = (char*)d_ws;
    float*  hA   = (float*)w;  w += (size_t)N_NODES * 64 * 4;   // 25.6 MB
    __half* h2h  = (__half*)w; w += (size_t)N_NODES * 64 * 2;   // 12.8 MB
    float*  as_  = (float*)w;  w += (size_t)N_NODES * 4;
    float*  ad_  = (float*)w;  w += (size_t)N_NODES * 4;
    int*    rp   = (int*)w;    w += 400016;                     // N+1 ints, padded
    int*    deg  = (int*)w;    w += (size_t)N_NODES * 4;
    int*    bsum = (int*)w;    w += 4096;
    int*    bcur = (int*)w;    w += ((NB + 1023) / 1024) * 4096; // 1563 ints, padded
    int*    col  = (int*)w;    w += (size_t)N_EDGES * 4;        // 12.8 MB
    int2*   pairs= (int2*)w;   w += (size_t)N_EDGES * 8;        // 25.6 MB

    // CSR build (dst-grouped; self-loops handled analytically in aggregation)
    hipMemsetAsync(deg, 0, (size_t)N_NODES * 4, stream);
    histo_kernel<<<2048, 256, 0, stream>>>(ei, deg);
    int nsb = (N_NODES + 1023) / 1024;  // 98
    scan_block_kernel<<<nsb, 1024, 0, stream>>>(deg, rp, bsum, N_NODES);
    scan_partials_kernel<<<1, 1024, 0, stream>>>(bsum, nsb);
    fixup_kernel<<<(N_NODES + 256) / 256, 256, 0, stream>>>(rp, bsum, N_NODES);
    init_bcursor_kernel<<<(NB + 255) / 256, 256, 0, stream>>>(rp, bcur);
    partition_kernel<<<2048, 256, 0, stream>>>(ei, bcur, pairs);
    bucket_fill_kernel<<<NB, 256, 0, stream>>>(rp, pairs, col);

    // input transform
    gemm_rt<<<(N_NODES + 63) / 64, 256, 0, stream>>>(x, W_in, b_in, hA, N_NODES, NFEAT);

    for (int l = 0; l < N_LAYERS; ++l) {
        gemm_fused<<<(N_NODES + 63) / 64, 256, 0, stream>>>(hA, W_conv + (size_t)l * 64 * 64,
                                                            att_src + l * 64, att_dst + l * 64,
                                                            as_, ad_, h2h, N_NODES);
        gat_aggregate<<<N_NODES / 4, 256, 0, stream>>>(rp, col, h2h, as_, ad_,
                                                       b_conv + l * 64, hA);
    }

    out_gemm<<<N_NODES / 4, 256, 0, stream>>>(hA, W_out, b_out, out);
}

// Round 4
// 1011.842 us; speedup vs baseline: 1.3342x; 1.3342x over previous
//
#include <hip/hip_runtime.h>
#include <hip/hip_bf16.h>
#include <hip/hip_fp16.h>

#define N_NODES 100000
#define N_EDGES 3200000
#define NFEAT 512
#define HDIM 64
#define NCLASS 40
#define N_LAYERS 4
#define NEG_SLOPE 0.2f

#define NSLICE 8
#define SL_W 12500   // nodes per slice (8 * 12500 = 100000)

__device__ __forceinline__ float leaky(float x) {
    return x >= 0.f ? x : NEG_SLOPE * x;
}

// ---------------- CSR build (XCD-sliced scatter) ----------------
// Block blockIdx&7 handles dst-slice blockIdx&7. With round-robin block->XCD
// dispatch, all writers of a slice's 1.6MB col/cur window sit on ONE XCD, so
// scatter lines accumulate in that XCD's L2 and write back to HBM once.

__global__ void histo_kernel(const int* __restrict__ ei, int* __restrict__ deg) {
    int slice = blockIdx.x & (NSLICE - 1);
    int nlo = slice * SL_W, nhi = nlo + SL_W;
    int bi = blockIdx.x >> 3;
    int stride = (gridDim.x >> 3) * blockDim.x;
    for (int e = bi * blockDim.x + threadIdx.x; e < N_EDGES; e += stride) {
        int d = ei[N_EDGES + e];
        if (d >= nlo && d < nhi) atomicAdd(&deg[d], 1);
    }
}

__global__ __launch_bounds__(1024) void scan_block_kernel(const int* __restrict__ deg,
                                                          int* __restrict__ rp,
                                                          int* __restrict__ bsum, int n) {
    __shared__ int s[1024];
    int t = threadIdx.x;
    int i = blockIdx.x * 1024 + t;
    int v = (i < n) ? deg[i] : 0;
    s[t] = v;
    __syncthreads();
    for (int off = 1; off < 1024; off <<= 1) {
        int x = (t >= off) ? s[t - off] : 0;
        __syncthreads();
        s[t] += x;
        __syncthreads();
    }
    if (i < n) rp[i] = s[t] - v;        // exclusive
    if (t == 1023) bsum[blockIdx.x] = s[t];
}

__global__ __launch_bounds__(1024) void scan_partials_kernel(int* __restrict__ bsum, int nb) {
    __shared__ int s[1024];
    int t = threadIdx.x;
    int v = (t < nb) ? bsum[t] : 0;
    s[t] = v;
    __syncthreads();
    for (int off = 1; off < 1024; off <<= 1) {
        int x = (t >= off) ? s[t - off] : 0;
        __syncthreads();
        s[t] += x;
        __syncthreads();
    }
    if (t < nb) bsum[t] = s[t] - v;     // exclusive
}

__global__ void fixup_kernel(int* __restrict__ rp, const int* __restrict__ bsum,
                             int* __restrict__ cur, int n) {
    int i = blockIdx.x * blockDim.x + threadIdx.x;
    if (i < n) {
        int v = rp[i] + bsum[i >> 10];
        rp[i] = v;
        cur[i] = v;
    }
    if (i == n) rp[n] = N_EDGES;
}

__global__ void fill_slice_kernel(const int* __restrict__ ei, int* __restrict__ cur,
                                  int* __restrict__ col) {
    int slice = blockIdx.x & (NSLICE - 1);
    int nlo = slice * SL_W, nhi = nlo + SL_W;
    int bi = blockIdx.x >> 3;
    int stride = (gridDim.x >> 3) * blockDim.x;
    for (int e = bi * blockDim.x + threadIdx.x; e < N_EDGES; e += stride) {
        int d = ei[N_EDGES + e];
        if (d >= nlo && d < nhi) {
            int s = ei[e];
            int p = atomicAdd(&cur[d], 1);
            col[p] = s;
        }
    }
}

// ---------------- GEMM: C[M x 64] = A[M x K] @ B[K x 64] + bias ----------------
// block 256 = 16x16 threads, tile 64x64, micro-tile 4x4, BK=16

__global__ __launch_bounds__(256) void gemm_rt(const float* __restrict__ A,
                                               const float* __restrict__ B,
                                               const float* __restrict__ bias,
                                               float* __restrict__ C, int M, int K) {
    __shared__ float As[16][65];  // [k][m], padded
    __shared__ float Bs[16][64];  // [k][n]
    int t = threadIdx.x;
    int tx = t & 15;
    int ty = t >> 4;
    int row0 = blockIdx.x * 64;
    float acc[4][4] = {};
    for (int kt = 0; kt < K; kt += 16) {
        {
            int r = t >> 2;
            int kk = (t & 3) << 2;
            int gr = row0 + r;
            float4 v = make_float4(0.f, 0.f, 0.f, 0.f);
            if (gr < M) v = *(const float4*)&A[(size_t)gr * K + kt + kk];
            As[kk + 0][r] = v.x;
            As[kk + 1][r] = v.y;
            As[kk + 2][r] = v.z;
            As[kk + 3][r] = v.w;
        }
        {
            int kk = t >> 4;
            int n0 = (t & 15) << 2;
            float4 v = *(const float4*)&B[(size_t)(kt + kk) * 64 + n0];
            *(float4*)&Bs[kk][n0] = v;
        }
        __syncthreads();
#pragma unroll
        for (int kk = 0; kk < 16; ++kk) {
            float a0 = As[kk][ty * 4 + 0];
            float a1 = As[kk][ty * 4 + 1];
            float a2 = As[kk][ty * 4 + 2];
            float a3 = As[kk][ty * 4 + 3];
            float4 b = *(float4*)&Bs[kk][tx * 4];
            acc[0][0] += a0 * b.x; acc[0][1] += a0 * b.y; acc[0][2] += a0 * b.z; acc[0][3] += a0 * b.w;
            acc[1][0] += a1 * b.x; acc[1][1] += a1 * b.y; acc[1][2] += a1 * b.z; acc[1][3] += a1 * b.w;
            acc[2][0] += a2 * b.x; acc[2][1] += a2 * b.y; acc[2][2] += a2 * b.z; acc[2][3] += a2 * b.w;
            acc[3][0] += a3 * b.x; acc[3][1] += a3 * b.y; acc[3][2] += a3 * b.z; acc[3][3] += a3 * b.w;
        }
        __syncthreads();
    }
#pragma unroll
    for (int i = 0; i < 4; ++i) {
        int gr = row0 + ty * 4 + i;
        if (gr < M) {
#pragma unroll
            for (int j = 0; j < 4; ++j) {
                int n = tx * 4 + j;
                float bv = bias ? bias[n] : 0.f;
                C[(size_t)gr * 64 + n] = acc[i][j] + bv;
            }
        }
    }
}

// ---------------- fused layer GEMM: h2 = A @ W, + att dots + fp16 convert ----------------

__global__ __launch_bounds__(256) void gemm_fused(const float* __restrict__ A,
                                                  const float* __restrict__ W,
                                                  const float* __restrict__ att_s_g,
                                                  const float* __restrict__ att_d_g,
                                                  float* __restrict__ as_,
                                                  float* __restrict__ ad_,
                                                  __half* __restrict__ h2h, int M) {
    __shared__ float As[16][65];
    __shared__ float Bs[16][64];
    __shared__ float2 red[64][17];   // padded: avoids bank conflicts in reduce
    __shared__ float sATT[128];
    int t = threadIdx.x;
    int tx = t & 15;
    int ty = t >> 4;
    int row0 = blockIdx.x * 64;
    if (t < 64) sATT[t] = att_s_g[t];
    else if (t < 128) sATT[t] = att_d_g[t - 64];
    float acc[4][4] = {};
    for (int kt = 0; kt < 64; kt += 16) {
        {
            int r = t >> 2;
            int kk = (t & 3) << 2;
            int gr = row0 + r;
            float4 v = make_float4(0.f, 0.f, 0.f, 0.f);
            if (gr < M) v = *(const float4*)&A[(size_t)gr * 64 + kt + kk];
            As[kk + 0][r] = v.x;
            As[kk + 1][r] = v.y;
            As[kk + 2][r] = v.z;
            As[kk + 3][r] = v.w;
        }
        {
            int kk = t >> 4;
            int n0 = (t & 15) << 2;
            float4 v = *(const float4*)&W[(size_t)(kt + kk) * 64 + n0];
            *(float4*)&Bs[kk][n0] = v;
        }
        __syncthreads();
#pragma unroll
        for (int kk = 0; kk < 16; ++kk) {
            float a0 = As[kk][ty * 4 + 0];
            float a1 = As[kk][ty * 4 + 1];
            float a2 = As[kk][ty * 4 + 2];
            float a3 = As[kk][ty * 4 + 3];
            float4 b = *(float4*)&Bs[kk][tx * 4];
            acc[0][0] += a0 * b.x; acc[0][1] += a0 * b.y; acc[0][2] += a0 * b.z; acc[0][3] += a0 * b.w;
            acc[1][0] += a1 * b.x; acc[1][1] += a1 * b.y; acc[1][2] += a1 * b.z; acc[1][3] += a1 * b.w;
            acc[2][0] += a2 * b.x; acc[2][1] += a2 * b.y; acc[2][2] += a2 * b.z; acc[2][3] += a2 * b.w;
            acc[3][0] += a3 * b.x; acc[3][1] += a3 * b.y; acc[3][2] += a3 * b.z; acc[3][3] += a3 * b.w;
        }
        __syncthreads();
    }
#pragma unroll
    for (int i = 0; i < 4; ++i) {
        float ps = acc[i][0] * sATT[tx * 4 + 0] + acc[i][1] * sATT[tx * 4 + 1] +
                   acc[i][2] * sATT[tx * 4 + 2] + acc[i][3] * sATT[tx * 4 + 3];
        float pd = acc[i][0] * sATT[64 + tx * 4 + 0] + acc[i][1] * sATT[64 + tx * 4 + 1] +
                   acc[i][2] * sATT[64 + tx * 4 + 2] + acc[i][3] * sATT[64 + tx * 4 + 3];
        red[ty * 4 + i][tx] = make_float2(ps, pd);
    }
    __syncthreads();
    if (t < 64) {
        float a = 0.f, b = 0.f;
#pragma unroll
        for (int k = 0; k < 16; ++k) {
            float2 v = red[t][k];
            a += v.x; b += v.y;
        }
        int gr = row0 + t;
        if (gr < M) { as_[gr] = a; ad_[gr] = b; }
    }
    __half2* h2h2 = (__half2*)h2h;
#pragma unroll
    for (int i = 0; i < 4; ++i) {
        int gr = row0 + ty * 4 + i;
        if (gr < M) {
            h2h2[(size_t)gr * 32 + tx * 2 + 0] = __floats2half2_rn(acc[i][0], acc[i][1]);
            h2h2[(size_t)gr * 32 + tx * 2 + 1] = __floats2half2_rn(acc[i][2], acc[i][3]);
        }
    }
}

// ---------------- GAT aggregation: wave per dst node, lane = feature ----------------

__global__ __launch_bounds__(256) void gat_aggregate(const int* __restrict__ rp,
                                                     const int* __restrict__ col,
                                                     const __half* __restrict__ h2h,
                                                     const float* __restrict__ as_,
                                                     const float* __restrict__ ad_,
                                                     const float* __restrict__ bias,
                                                     float* __restrict__ h /* in/out */) {
    int wid = blockIdx.x * (blockDim.x >> 6) + (threadIdx.x >> 6);
    int lane = threadIdx.x & 63;
    if (wid >= N_NODES) return;
    int beg = rp[wid];
    int end = rp[wid + 1];
    float adv = ad_[wid];
    float e_self = leaky(as_[wid] + adv);

    // phase 1: max over incoming edges + self
    float mloc = e_self;
    for (int j = beg + lane; j < end; j += 64) {
        mloc = fmaxf(mloc, leaky(as_[col[j]] + adv));
    }
#pragma unroll
    for (int off = 32; off; off >>= 1) mloc = fmaxf(mloc, __shfl_xor(mloc, off));
    float m = mloc;

    // phase 2: weighted accumulation
    float w_self = __expf(e_self - m);
    float acc = w_self * __half2float(h2h[(size_t)wid * 64 + lane]);
    float wpart = 0.f;
    for (int j0 = beg; j0 < end; j0 += 64) {
        int rem = end - j0;
        int cnt = rem < 64 ? rem : 64;
        int s = 0;
        float w = 0.f;
        if (lane < cnt) {
            s = col[j0 + lane];
            w = __expf(leaky(as_[s] + adv) - m);
        }
        wpart += w;
        int j = 0;
        for (; j + 4 <= cnt; j += 4) {
            float w0 = __shfl(w, j), w1 = __shfl(w, j + 1);
            float w2 = __shfl(w, j + 2), w3 = __shfl(w, j + 3);
            int s0 = __shfl(s, j), s1 = __shfl(s, j + 1);
            int s2 = __shfl(s, j + 2), s3 = __shfl(s, j + 3);
            float v0 = __half2float(h2h[(size_t)s0 * 64 + lane]);
            float v1 = __half2float(h2h[(size_t)s1 * 64 + lane]);
            float v2 = __half2float(h2h[(size_t)s2 * 64 + lane]);
            float v3 = __half2float(h2h[(size_t)s3 * 64 + lane]);
            acc += w0 * v0;
            acc += w1 * v1;
            acc += w2 * v2;
            acc += w3 * v3;
        }
        for (; j < cnt; ++j) {
            float wj = __shfl(w, j);
            int sj = __shfl(s, j);
            acc += wj * __half2float(h2h[(size_t)sj * 64 + lane]);
        }
    }
#pragma unroll
    for (int off = 32; off; off >>= 1) wpart += __shfl_xor(wpart, off);
    float denom = wpart + w_self;

    float o = acc / denom + bias[lane];
    float e = (o > 0.f) ? o : expm1f(o);
    size_t idx = (size_t)wid * 64 + lane;
    h[idx] = h[idx] + e;   // residual, in place (own row only)
}

// ---------------- output GEMM: out[N x 40] = h[N x 64] @ W[64 x 40] + b ----------------

__global__ __launch_bounds__(256) void out_gemm(const float* __restrict__ h,
                                                const float* __restrict__ W,
                                                const float* __restrict__ b,
                                                float* __restrict__ out) {
    __shared__ float Ws[64 * 40];
    __shared__ float bs[40];
    int t = threadIdx.x;
    for (int idx = t; idx < 64 * 40; idx += 256) Ws[idx] = W[idx];
    if (t < 40) bs[t] = b[t];
    __syncthreads();
    int wid = blockIdx.x * (blockDim.x >> 6) + (t >> 6);
    int lane = t & 63;
    if (wid >= N_NODES) return;
    float hv = h[(size_t)wid * 64 + lane];
    float acc = (lane < 40) ? bs[lane] : 0.f;
#pragma unroll
    for (int k = 0; k < 64; ++k) {
        float hk = __shfl(hv, k);
        float wv = (lane < 40) ? Ws[k * 40 + lane] : 0.f;
        acc += hk * wv;
    }
    if (lane < 40) out[(size_t)wid * 40 + lane] = acc;
}

// ---------------- launcher ----------------

extern "C" void kernel_launch(void* const* d_in, const int* in_sizes, int n_in,
                              void* d_out, int out_size, void* d_ws, size_t ws_size,
                              hipStream_t stream) {
    const float* x        = (const float*)d_in[0];
    const int* ei         = (const int*)d_in[1];   // harness passes integers as int32
    const float* W_in     = (const float*)d_in[2];
    const float* b_in     = (const float*)d_in[3];
    const float* W_conv   = (const float*)d_in[4];
    const float* att_src  = (const float*)d_in[5];
    const float* att_dst  = (const float*)d_in[6];
    const float* b_conv   = (const float*)d_in[7];
    const float* W_out    = (const float*)d_in[8];
    const float* b_out    = (const float*)d_in[9];
    float* out = (float*)d_out;

    char* w = (char*)d_ws;
    float*  hA   = (float*)w;  w += (size_t)N_NODES * 64 * 4;   // 25.6 MB
    __half* h2h  = (__half*)w; w += (size_t)N_NODES * 64 * 2;   // 12.8 MB
    float*  as_  = (float*)w;  w += (size_t)N_NODES * 4;
    float*  ad_  = (float*)w;  w += (size_t)N_NODES * 4;
    int*    rp   = (int*)w;    w += 400016;                     // N+1 ints, padded
    int*    cur  = (int*)w;    w += (size_t)N_NODES * 4;        // degrees, then cursors
    int*    bsum = (int*)w;    w += 4096;
    int*    col  = (int*)w;    w += (size_t)N_EDGES * 4;        // 12.8 MB

    // CSR build (dst-grouped; self-loops handled analytically in aggregation)
    hipMemsetAsync(cur, 0, (size_t)N_NODES * 4, stream);
    histo_kernel<<<2048, 256, 0, stream>>>(ei, cur);
    int nsb = (N_NODES + 1023) / 1024;  // 98
    scan_block_kernel<<<nsb, 1024, 0, stream>>>(cur, rp, bsum, N_NODES);
    scan_partials_kernel<<<1, 1024, 0, stream>>>(bsum, nsb);
    fixup_kernel<<<(N_NODES + 256) / 256, 256, 0, stream>>>(rp, bsum, cur, N_NODES);
    fill_slice_kernel<<<2048, 256, 0, stream>>>(ei, cur, col);

    // input transform
    gemm_rt<<<(N_NODES + 63) / 64, 256, 0, stream>>>(x, W_in, b_in, hA, N_NODES, NFEAT);

    for (int l = 0; l < N_LAYERS; ++l) {
        gemm_fused<<<(N_NODES + 63) / 64, 256, 0, stream>>>(hA, W_conv + (size_t)l * 64 * 64,
                                                            att_src + l * 64, att_dst + l * 64,
                                                            as_, ad_, h2h, N_NODES);
        gat_aggregate<<<N_NODES / 4, 256, 0, stream>>>(rp, col, h2h, as_, ad_,
                                                       b_conv + l * 64, hA);
    }

    out_gemm<<<N_NODES / 4, 256, 0, stream>>>(hA, W_out, b_out, out);
}